// Round 18
// baseline (285.253 us; speedup 1.0000x reference)
//
#include <hip/hip_runtime.h>
#include <hip/hip_bf16.h>

#define B_   8
#define T_   2048
#define EMB_ 1024
#define ND_  1024
#define NTB2 8      // T_/256

typedef __attribute__((ext_vector_type(8))) short   bf8_t;   // 8 bf16 elements (4 VGPRs)
typedef __attribute__((ext_vector_type(4))) float   f32x4;

__device__ __forceinline__ unsigned short f2bf(float f) {
  union { float f; unsigned int u; } c; c.f = f;
  unsigned int u = c.u;
  unsigned int r = (u + 0x7FFFu + ((u >> 16) & 1u)) >> 16;
  return (unsigned short)r;
}

__device__ __forceinline__ float bf2f(unsigned short b) {
  union { unsigned int u; float f; } c; c.u = ((unsigned int)b) << 16;
  return c.f;
}

__device__ __forceinline__ void gload_lds16(const unsigned short* g, unsigned short* l) {
  __builtin_amdgcn_global_load_lds(
      (const __attribute__((address_space(1))) unsigned int*)g,
      (__attribute__((address_space(3))) unsigned int*)l,
      16, 0, 0);
}

__device__ __forceinline__ void tri_decode(int p, int& tblk, int& sblk) {
  int t = (int)((sqrtf(8.0f * (float)p + 1.0f) - 1.0f) * 0.5f);
  while ((t + 1) * (t + 2) / 2 <= p) ++t;
  while (t * (t + 1) / 2 > p) --t;
  tblk = t;
  sblk = p - t * (t + 1) / 2;
}

#define SB0() __builtin_amdgcn_sched_barrier(0)
#define BAR() __builtin_amdgcn_s_barrier()

// Stage one 128x64 bf16 half-tile (8192 shorts = 16 KiB; 2 gloads/wave).
__device__ __forceinline__ void stage_half(const unsigned short* __restrict__ g, int lda,
                                           unsigned short* lhalf, int wave, int lane) {
  const int r3 = lane >> 3, c3 = lane & 7;
  const int colsw = ((c3 ^ r3) << 3);
#pragma unroll
  for (int j = 0; j < 2; ++j) {
    const int row = wave * 8 + r3 + 64 * j;
    gload_lds16(g + (size_t)row * lda + colsw, lhalf + wave * 512 + j * 4096);
  }
}

// Read one bf16x8 MFMA fragment at half-local row r, K-subtile ks (64-col rows).
__device__ __forceinline__ bf8_t read_frag(const unsigned short* half, int r, int ks, int lane) {
  const int col = (((ks) << 5) + ((lane >> 4) << 3)) ^ ((r & 7) << 3);
  return *(const bf8_t*)(half + r * 64 + col);
}

// ---- BK=32 variants: 128x32 tile = 8 KiB, 1 gload/wave. Linear [128][32] dest. ----
// Each wave covers 16 rows x 32 shorts = 512 shorts (wave*512 base!).
// Swizzle: granule' = granule ^ ((r>>1)&3)  (2-way max bank alias -> free).
__device__ __forceinline__ void stage_q32(const unsigned short* __restrict__ g, int lda,
                                          unsigned short* ldsq, int wave, int lane) {
  const int r = wave * 16 + (lane >> 2);
  const int colsw = (((lane & 3) ^ ((r >> 1) & 3)) << 3);
  gload_lds16(g + (size_t)r * lda + colsw, ldsq + wave * 512);
}

__device__ __forceinline__ bf8_t read_frag32(const unsigned short* q, int r, int lane) {
  const int col = (((lane >> 4) ^ ((r >> 1) & 3)) << 3);
  return *(const bf8_t*)(q + r * 32 + col);
}

// Epilogue LDS swizzle for 256-B rows, 16-B granules.
__device__ __forceinline__ int swz_ep2(int r) { return (r & 7) << 4; }
// 512-B-row variant.
__device__ __forceinline__ int swz_ep(int x) { return ((x >> 1) & 7) << 4; }

// ---------------- X -> bf16 ----------------
__global__ void __launch_bounds__(256) cvt_x_kernel(const float* __restrict__ in,
                                                    unsigned short* __restrict__ out) {
  const int i = (blockIdx.x * 256 + threadIdx.x) * 4;
  float4 v = *(const float4*)(in + i);
  ushort4 o = make_ushort4(f2bf(v.x), f2bf(v.y), f2bf(v.z), f2bf(v.w));
  *(ushort4*)(out + i) = o;
}

// ---------------- W [K][N] f32 -> Wt3 rows [N][K] bf16 (z selects source) ----------------
__global__ void __launch_bounds__(256) transpose_w3_kernel(const float* __restrict__ Wq,
                                                           const float* __restrict__ Wk,
                                                           const float* __restrict__ Wv,
                                                           unsigned short* __restrict__ Wt3) {
  __shared__ unsigned short tile[32][33];
  const int z = blockIdx.z;
  const float* W = (z == 0) ? Wq : (z == 1) ? Wk : Wv;
  const float cscale = (z == 0) ? 0.03125f : 1.0f;
  unsigned short* Wt = Wt3 + (size_t)z * ND_ * EMB_;
  const int n0 = blockIdx.x * 32, k0 = blockIdx.y * 32;
  const int tx = threadIdx.x & 31, ty = threadIdx.x >> 5;
#pragma unroll
  for (int r = 0; r < 32; r += 8) {
    float v = W[(size_t)(k0 + ty + r) * ND_ + n0 + tx];
    tile[tx][ty + r] = f2bf(v * cscale);
  }
  __syncthreads();
#pragma unroll
  for (int r = 0; r < 32; r += 8) {
    Wt[(size_t)(n0 + ty + r) * EMB_ + k0 + tx] = tile[ty + r][tx];
  }
}

// ================= shared MFMA quad macros =================
#define MFMA_QUAD(MB, AF, AOFF) do { \
  __builtin_amdgcn_s_setprio(1); \
  _Pragma("unroll") \
  for (int mi = 0; mi < 2; ++mi) \
    _Pragma("unroll") \
    for (int nf = 0; nf < 4; ++nf) \
      _Pragma("unroll") \
      for (int ks = 0; ks < 2; ++ks) \
        acc[(MB) * 2 + mi][nf] = __builtin_amdgcn_mfma_f32_16x16x32_bf16( \
            (AF)[(AOFF) + mi][ks], bfr[nf][ks], acc[(MB) * 2 + mi][nf], 0, 0, 0); \
  __builtin_amdgcn_s_setprio(0); \
} while (0)

#define MFMA_Q8(MB) do { \
  __builtin_amdgcn_s_setprio(1); \
  _Pragma("unroll") \
  for (int nf = 0; nf < 4; ++nf) \
    _Pragma("unroll") \
    for (int ks = 0; ks < 2; ++ks) \
      acc[(MB)][nf] = __builtin_amdgcn_mfma_f32_16x16x32_bf16( \
          af[(MB)][ks], bfr[nf][ks], acc[(MB)][nf], 0, 0, 0); \
  __builtin_amdgcn_s_setprio(0); \
} while (0)

// BK=32 quad: 4 MFMAs (mf pair x nf 0..1, single K step).
#define MFMA_K32(MB) do { \
  __builtin_amdgcn_s_setprio(1); \
  _Pragma("unroll") \
  for (int mi = 0; mi < 2; ++mi) \
    _Pragma("unroll") \
    for (int nf = 0; nf < 2; ++nf) \
      acc[(MB) * 2 + mi][nf] = __builtin_amdgcn_mfma_f32_16x16x32_bf16( \
          af[(MB) * 2 + mi], bfr[nf], acc[(MB) * 2 + mi][nf], 0, 0, 0); \
  __builtin_amdgcn_s_setprio(0); \
} while (0)

// ================= 256x256 8-phase core, distance-2 prefetch (proven; xw) =========
#define LDSA(d, h) (lds256 + ((d) * 2 + (h)) * 8192)
#define LDSB(d, h) (lds256 + 32768 + ((d) * 2 + (h)) * 8192)

#define GEMM256_LOOP(ABASE, BBASE, LDK) \
  stage_half((ABASE),                             (LDK), LDSA(0, 0), wave, lane); \
  stage_half((ABASE) + (size_t)128 * (LDK),       (LDK), LDSA(0, 1), wave, lane); \
  stage_half((BBASE),                             (LDK), LDSB(0, 0), wave, lane); \
  stage_half((BBASE) + (size_t)128 * (LDK),       (LDK), LDSB(0, 1), wave, lane); \
  stage_half((BBASE) + 64,                        (LDK), LDSB(1, 0), wave, lane); \
  stage_half((BBASE) + (size_t)128 * (LDK) + 64,  (LDK), LDSB(1, 1), wave, lane); \
  stage_half((ABASE) + 64,                        (LDK), LDSA(1, 0), wave, lane); \
  stage_half((ABASE) + (size_t)128 * (LDK) + 64,  (LDK), LDSA(1, 1), wave, lane); \
  asm volatile("s_waitcnt vmcnt(8)" ::: "memory"); \
  SB0(); BAR(); SB0(); \
  for (int t = 0; t < 16; ++t) { \
    const int d = t & 1; \
    const unsigned short* Ah = LDSA(d, wm); \
    const unsigned short* Bh = LDSB(d, wn >> 1); \
    bf8_t bfr[4][2], af[4][2]; \
    _Pragma("unroll") \
    for (int nf = 0; nf < 4; ++nf) \
      _Pragma("unroll") \
      for (int ks = 0; ks < 2; ++ks) bfr[nf][ks] = read_frag(Bh, brow + nf * 16, ks, lane); \
    _Pragma("unroll") \
    for (int mf = 0; mf < 4; ++mf) \
      _Pragma("unroll") \
      for (int ks = 0; ks < 2; ++ks) af[mf][ks] = read_frag(Ah, arow + mf * 16, ks, lane); \
    SB0(); BAR(); SB0(); \
    MFMA_QUAD(0, af, 0); \
    SB0(); \
    asm volatile("s_waitcnt lgkmcnt(0)" ::: "memory"); \
    SB0(); BAR(); SB0(); \
    if (t < 14) { \
      stage_half((BBASE) + (size_t)(t + 2) * 64,                     (LDK), LDSB(d, 0), wave, lane); \
      stage_half((BBASE) + (size_t)128 * (LDK) + (size_t)(t + 2) * 64,(LDK), LDSB(d, 1), wave, lane); \
    } \
    SB0(); BAR(); SB0(); \
    MFMA_QUAD(1, af, 2); \
    SB0(); BAR(); SB0(); \
    bf8_t af2[4][2]; \
    _Pragma("unroll") \
    for (int mf = 0; mf < 4; ++mf) \
      _Pragma("unroll") \
      for (int ks = 0; ks < 2; ++ks) af2[mf][ks] = read_frag(Ah, arow + (mf + 4) * 16, ks, lane); \
    SB0(); BAR(); SB0(); \
    MFMA_QUAD(2, af2, 0); \
    SB0(); \
    asm volatile("s_waitcnt lgkmcnt(0)" ::: "memory"); \
    SB0(); BAR(); SB0(); \
    if (t < 14) { \
      stage_half((ABASE) + (size_t)(t + 2) * 64,                     (LDK), LDSA(d, 0), wave, lane); \
      stage_half((ABASE) + (size_t)128 * (LDK) + (size_t)(t + 2) * 64,(LDK), LDSA(d, 1), wave, lane); \
      asm volatile("s_waitcnt vmcnt(8)" ::: "memory"); \
    } else if (t == 14) { \
      asm volatile("s_waitcnt vmcnt(0)" ::: "memory"); \
    } \
    SB0(); BAR(); SB0(); \
    MFMA_QUAD(3, af2, 2); \
    SB0(); BAR(); SB0(); \
  }

// ========== projection GEMM: C = Xb @ Wt^T (r15-proven 3-dispatch, 128 KiB LDS) ==========
template <int OUTMODE>
__global__ void __launch_bounds__(512, 2)
gemm_xw256_kernel(const unsigned short* __restrict__ A,
                  const unsigned short* __restrict__ Bt,
                  unsigned short* __restrict__ C) {
  extern __shared__ unsigned short lds256[];
  const int tid = threadIdx.x, lane = tid & 63, wave = tid >> 6;
  const int wm = wave >> 2, wn = wave & 3;
  const int m0 = blockIdx.y * 256, n0 = blockIdx.x * 256;
  const unsigned short* Ab = A + (size_t)m0 * EMB_;
  const unsigned short* Bb = Bt + (size_t)n0 * EMB_;
  f32x4 acc[8][4];
#pragma unroll
  for (int i = 0; i < 8; ++i)
#pragma unroll
    for (int j = 0; j < 4; ++j)
#pragma unroll
      for (int q = 0; q < 4; ++q) acc[i][j][q] = 0.f;
  const int arow = lane & 15;
  const int brow = (wn & 1) * 64 + (lane & 15);

  GEMM256_LOOP(Ab, Bb, EMB_)

  const int cc = lane & 15, cr4 = (lane >> 4) << 2;
#pragma unroll
  for (int mf = 0; mf < 8; ++mf)
#pragma unroll
    for (int nf = 0; nf < 4; ++nf)
#pragma unroll
      for (int q = 0; q < 4; ++q) {
        const int r = wm * 128 + mf * 16 + cr4 + q;
        const int c = wn * 64 + nf * 16 + cc;
        const unsigned short bv = f2bf(acc[mf][nf][q]);
        const int byte = (OUTMODE == 1) ? (c * 512 + ((r * 2) ^ swz_ep(c)))
                                        : (r * 512 + ((c * 2) ^ swz_ep(r)));
        lds256[byte >> 1] = bv;
      }
  __syncthreads();
  if (OUTMODE == 0) {
#pragma unroll
    for (int p = 0; p < 16; ++p) {
      const int o = p * 8192 + tid * 16;
      const int ri = o >> 9, cb = o & 511;
      const bf8_t v = *(const bf8_t*)(lds256 + (((o & ~511) | (cb ^ swz_ep(ri))) >> 1));
      *(bf8_t*)(C + (size_t)(m0 + ri) * ND_ + n0 + (cb >> 1)) = v;
    }
  } else {
    const int bb = m0 >> 11, tt0 = m0 & 2047;
#pragma unroll
    for (int p = 0; p < 16; ++p) {
      const int o = p * 8192 + tid * 16;
      const int ci = o >> 9, rb = o & 511;
      const bf8_t v = *(const bf8_t*)(lds256 + (((o & ~511) | (rb ^ swz_ep(ci))) >> 1));
      *(bf8_t*)(C + ((size_t)bb * ND_ + n0 + ci) * T_ + tt0 + (rb >> 1)) = v;
    }
  }
}

// ========== scoretile1088 @ BK=32, 32 KiB LDS, target 4 blocks/CU ==========
// LDS (shorts): A(d) at d*4096, B(d) at 8192 + d*4096. 16384 shorts = 32 KiB.
// Ledger/wave: 1 load per stage_q32; 2 loads/K-tile. Prologue 4 -> vmcnt(2).
// Per tile: stage A(t+2),B(t+2) after lgkmcnt-guarded barrier; vmcnt(2) completes t+1.
__global__ void __launch_bounds__(512, 8)
scoretile1088_kernel(const unsigned short* __restrict__ Qb,
                     const unsigned short* __restrict__ Kb,
                     unsigned short* __restrict__ Pp,
                     float* __restrict__ pm) {
  extern __shared__ unsigned short lds256[];
  const int id = blockIdx.x;
  const int b = id & 7;
  int tb, sb;
  tri_decode(id >> 3, tb, sb);
  const int t0 = tb * 128, s0 = sb * 128;
  const int tid = threadIdx.x, lane = tid & 63, wave = tid >> 6;
  const int wm = wave >> 2, wn = wave & 3;
  const int arow = lane & 15;
  const unsigned short* Ab = Qb + ((size_t)b * T_ + t0) * ND_;
  const unsigned short* Bb = Kb + ((size_t)b * T_ + s0) * ND_;
  f32x4 acc[4][2];
#pragma unroll
  for (int i = 0; i < 4; ++i)
#pragma unroll
    for (int j = 0; j < 2; ++j)
#pragma unroll
      for (int q = 0; q < 4; ++q) acc[i][j][q] = 0.f;

  stage_q32(Ab,      ND_, lds256,         wave, lane);   // A t0
  stage_q32(Bb,      ND_, lds256 + 8192,  wave, lane);   // B t0
  stage_q32(Ab + 32, ND_, lds256 + 4096,  wave, lane);   // A t1
  stage_q32(Bb + 32, ND_, lds256 + 12288, wave, lane);   // B t1
  asm volatile("s_waitcnt vmcnt(2)" ::: "memory");
  SB0(); BAR(); SB0();

  for (int t = 0; t < 32; ++t) {
    const int d = t & 1;
    const unsigned short* Ah = lds256 + d * 4096;
    const unsigned short* Bh = lds256 + 8192 + d * 4096;
    bf8_t bfr[2], af[4];
#pragma unroll
    for (int nf = 0; nf < 2; ++nf)
      bfr[nf] = read_frag32(Bh, wn * 32 + nf * 16 + arow, lane);
#pragma unroll
    for (int mf = 0; mf < 4; ++mf)
      af[mf] = read_frag32(Ah, wm * 64 + mf * 16 + arow, lane);
    SB0(); BAR(); SB0();
    MFMA_K32(0);
    SB0();
    asm volatile("s_waitcnt lgkmcnt(0)" ::: "memory");
    SB0(); BAR(); SB0();
    if (t < 30) {
      stage_q32(Ab + (size_t)(t + 2) * 32, ND_, lds256 + d * 4096, wave, lane);
      stage_q32(Bb + (size_t)(t + 2) * 32, ND_, lds256 + 8192 + d * 4096, wave, lane);
    }
    SB0(); BAR(); SB0();
    MFMA_K32(1);
    SB0();
    if (t < 30)      { asm volatile("s_waitcnt vmcnt(2)" ::: "memory"); }
    else if (t == 30){ asm volatile("s_waitcnt vmcnt(0)" ::: "memory"); }
    SB0(); BAR(); SB0();
  }

  // ---- epilogue: P' = exp(S) (masked) into LDS (128x128, 256-B rows) + col sums ----
  __syncthreads();
  const int cc = lane & 15, cr4 = (lane >> 4) << 2;
  const bool diag = (tb == sb);
  float csum[2];
#pragma unroll
  for (int nf = 0; nf < 2; ++nf) csum[nf] = 0.f;
#pragma unroll
  for (int mf = 0; mf < 4; ++mf)
#pragma unroll
    for (int nf = 0; nf < 2; ++nf)
#pragma unroll
      for (int q = 0; q < 4; ++q) {
        const int rr = wm * 64 + mf * 16 + cr4 + q;   // 0..127
        const int c  = wn * 32 + nf * 16 + cc;        // 0..127
        const bool ok = !diag || ((t0 + rr) >= (s0 + c));
        unsigned short bv = 0;
        if (ok) {
          bv = f2bf(__expf(fminf(acc[mf][nf][q], 30.f)));
          csum[nf] += bf2f(bv);
        }
        lds256[(rr * 256 + ((c * 2) ^ swz_ep2(rr))) >> 1] = bv;
      }
  __syncthreads();
  unsigned short* Pbase = Pp + (size_t)b * T_ * T_;
#pragma unroll
  for (int p = 0; p < 4; ++p) {
    const int o = p * 8192 + tid * 16;
    const int ri = o >> 8, cb = o & 255;
    const bf8_t v = *(const bf8_t*)(lds256 + (((o & ~255) | (cb ^ swz_ep2(ri))) >> 1));
    *(bf8_t*)(Pbase + (size_t)(t0 + ri) * T_ + s0 + (cb >> 1)) = v;
  }
#pragma unroll
  for (int nf = 0; nf < 2; ++nf) {
    csum[nf] += __shfl_xor(csum[nf], 16);
    csum[nf] += __shfl_xor(csum[nf], 32);
  }
  __syncthreads();
  float* red = (float*)lds256;   // [2 wm][4 wn][2 nf][16]
  if (lane < 16) {
#pragma unroll
    for (int nf = 0; nf < 2; ++nf)
      red[((wm * 4 + wn) * 2 + nf) * 16 + lane] = csum[nf];
  }
  __syncthreads();
  if (wm == 0 && lane < 16) {
    const size_t base = (((size_t)b * 16 + sb) * 16 + tb) * 128;
#pragma unroll
    for (int nf = 0; nf < 2; ++nf) {
      const float s = red[((0 * 4 + wn) * 2 + nf) * 16 + lane] +
                      red[((1 * 4 + wn) * 2 + nf) * 16 + lane];
      pm[base + wn * 32 + nf * 16 + lane] = s;
    }
  }
}

// ---------------- c_s = 1 / (sum of per-tile column sums), 128-granularity ----------------
__global__ void __launch_bounds__(128) colreduce_kernel(const float* __restrict__ pm,
                                                        float* __restrict__ colinv) {
  const int sb = blockIdx.x, b = blockIdx.y, c = threadIdx.x;
  float l = 0.f;
  for (int tb = sb; tb < 16; ++tb)
    l += pm[(((size_t)b * 16 + sb) * 16 + tb) * 128 + c];
  colinv[(size_t)b * T_ + sb * 128 + c] = 1.0f / l;
}

// ---------------- V''[b][d][s] = Vt[b][d][s] * c[b][s] (in place) ----------------
__global__ void __launch_bounds__(256) vscale_kernel(unsigned short* __restrict__ Vt,
                                                     const float* __restrict__ colinv) {
  const int idx = blockIdx.x * 256 + threadIdx.x;
  const int s8 = (idx * 8) & (T_ - 1);
  const int bd = idx / (T_ / 8);     // b*ND + d
  const int b = bd >> 10;
  unsigned short* p = Vt + (size_t)bd * T_ + s8;
  bf8_t v = *(bf8_t*)p;
#pragma unroll
  for (int j = 0; j < 8; ++j) {
    const float f = bf2f((unsigned short)v[j]) * colinv[(size_t)b * T_ + s8 + j];
    v[j] = (short)f2bf(f);
  }
  *(bf8_t*)p = v;
}

// ========== PV: BM=128 x BN=256, 3 halves/K-tile, distance-2 prefetch (r15-proven) ==========
__device__ __forceinline__ void pv_segment(const unsigned short* __restrict__ Ab,
                                           const unsigned short* __restrict__ Bb,
                                           float* __restrict__ Cb,
                                           int ktiles, unsigned short* lds256,
                                           int lane, int wave) {
  const int wm = wave >> 2, wn = wave & 3;
  const int arow = lane & 15;
  f32x4 acc[4][4];
#pragma unroll
  for (int i = 0; i < 4; ++i)
#pragma unroll
    for (int j = 0; j < 4; ++j)
#pragma unroll
      for (int q = 0; q < 4; ++q) acc[i][j][q] = 0.f;

  stage_half(Ab,                           T_, lds256,                     wave, lane);
  stage_half(Bb,                           T_, lds256 + 16384,             wave, lane);
  stage_half(Bb + (size_t)128 * T_,        T_, lds256 + 16384 + 8192,      wave, lane);
  stage_half(Ab + 64,                      T_, lds256 + 8192,              wave, lane);
  stage_half(Bb + 64,                      T_, lds256 + 16384 + 2 * 8192,  wave, lane);
  stage_half(Bb + (size_t)128 * T_ + 64,   T_, lds256 + 16384 + 3 * 8192,  wave, lane);
  asm volatile("s_waitcnt vmcnt(6)" ::: "memory");
  SB0(); BAR(); SB0();

  for (int t = 0; t < ktiles; ++t) {
    const int d = t & 1;
    const unsigned short* Ah = lds256 + d * 8192;
    const unsigned short* Bh = lds256 + 16384 + (d * 2 + (wn >> 1)) * 8192;
    bf8_t bfr[4][2], af[4][2];
#pragma unroll
    for (int nf = 0; nf < 4; ++nf)
#pragma unroll
      for (int ks = 0; ks < 2; ++ks)
        bfr[nf][ks] = read_frag(Bh, (wn & 1) * 64 + nf * 16 + arow, ks, lane);
#pragma unroll
    for (int mf = 0; mf < 4; ++mf)
#pragma unroll
      for (int ks = 0; ks < 2; ++ks)
        af[mf][ks] = read_frag(Ah, wm * 64 + mf * 16 + arow, ks, lane);
    SB0(); BAR(); SB0();
    MFMA_Q8(0);
    SB0();
    asm volatile("s_waitcnt lgkmcnt(0)" ::: "memory");
    SB0(); BAR(); SB0();
    if (t < ktiles - 2) {
      stage_half(Ab + (size_t)(t + 2) * 64, T_, lds256 + d * 8192, wave, lane);
      stage_half(Bb + (size_t)(t + 2) * 64, T_, lds256 + 16384 + (d * 2) * 8192, wave, lane);
    }
    SB0(); BAR(); SB0();
    MFMA_Q8(1);
    SB0(); BAR(); SB0();
    if (t < ktiles - 2)
      stage_half(Bb + (size_t)128 * T_ + (size_t)(t + 2) * 64, T_, lds256 + 16384 + (d * 2 + 1) * 8192, wave, lane);
    SB0(); BAR(); SB0();
    MFMA_Q8(2);
    SB0(); BAR(); SB0();
    if (t < ktiles - 2)      { asm volatile("s_waitcnt vmcnt(6)" ::: "memory"); }
    else if (t == ktiles - 2){ asm volatile("s_waitcnt vmcnt(0)" ::: "memory"); }
    SB0(); BAR(); SB0();
    MFMA_Q8(3);
    SB0(); BAR(); SB0();
  }

  const int cc = lane & 15, cr4 = (lane >> 4) << 2;
#pragma unroll
  for (int mf = 0; mf < 4; ++mf)
#pragma unroll
    for (int nf = 0; nf < 4; ++nf)
#pragma unroll
      for (int q = 0; q < 4; ++q) {
        const int row = wm * 64 + mf * 16 + cr4 + q;
        const int col = wn * 64 + nf * 16 + cc;
        Cb[(size_t)row * ND_ + col] = acc[mf][nf][q];
      }
}

// Paired triangular PV: block handles t-blocks {pair, 15-pair} -> uniform 34 K-tiles.
__global__ void __launch_bounds__(512, 2)
gemm_pv256_kernel(const unsigned short* __restrict__ Pb,
                  const unsigned short* __restrict__ Vt,
                  float* __restrict__ out) {
  extern __shared__ unsigned short lds256[];
  const int b = blockIdx.x & 7;
  const int pair = (blockIdx.x >> 3) & 7;
  const int ncol = blockIdx.x >> 6;
  const int lane = threadIdx.x & 63, wave = threadIdx.x >> 6;
  const int tbs[2] = {pair, 15 - pair};
#pragma unroll
  for (int si = 0; si < 2; ++si) {
    const int tb = tbs[si];
    const int ktiles = 2 * tb + 2;
    pv_segment(Pb + (size_t)b * T_ * T_ + (size_t)tb * 128 * T_,
               Vt + (size_t)b * ND_ * T_ + (size_t)ncol * 256 * T_,
               out + (size_t)b * T_ * ND_ + (size_t)tb * 128 * ND_ + ncol * 256,
               ktiles, lds256, lane, wave);
  }
}

extern "C" void kernel_launch(void* const* d_in, const int* in_sizes, int n_in,
                              void* d_out, int out_size, void* d_ws, size_t ws_size,
                              hipStream_t stream) {
  const float* X  = (const float*)d_in[0];
  const float* Wq = (const float*)d_in[1];
  const float* Wk = (const float*)d_in[2];
  const float* Wv = (const float*)d_in[3];
  float* out = (float*)d_out;
  (void)in_sizes; (void)n_in; (void)out_size;

  char* ws = (char*)d_ws;
  size_t off = 0;
  auto alloc = [&](size_t bytes) {
    void* p = ws + off;
    off += (bytes + 255) & ~(size_t)255;
    return p;
  };
  unsigned short* Xb  = (unsigned short*)alloc((size_t)B_ * T_ * EMB_ * 2);
  unsigned short* Wt3 = (unsigned short*)alloc((size_t)3 * ND_ * EMB_ * 2);
  unsigned short* Qb  = (unsigned short*)alloc((size_t)B_ * T_ * ND_ * 2);
  unsigned short* Kb  = (unsigned short*)alloc((size_t)B_ * T_ * ND_ * 2);
  unsigned short* Vt  = (unsigned short*)alloc((size_t)B_ * ND_ * T_ * 2);
  float* colinv = (float*)alloc((size_t)B_ * T_ * 4);
  float* pm     = (float*)alloc((size_t)B_ * 16 * 16 * 128 * 4);
  unsigned short* Pb  = (unsigned short*)alloc((size_t)B_ * T_ * T_ * 2);
  if (off > ws_size) return;

  hipFuncSetAttribute((const void*)&gemm_xw256_kernel<0>,
                      hipFuncAttributeMaxDynamicSharedMemorySize, 131072);
  hipFuncSetAttribute((const void*)&gemm_xw256_kernel<1>,
                      hipFuncAttributeMaxDynamicSharedMemorySize, 131072);
  hipFuncSetAttribute((const void*)&scoretile1088_kernel,
                      hipFuncAttributeMaxDynamicSharedMemorySize, 32768);
  hipFuncSetAttribute((const void*)&gemm_pv256_kernel,
                      hipFuncAttributeMaxDynamicSharedMemorySize, 98304);

  hipLaunchKernelGGL(cvt_x_kernel, dim3((B_ * T_ * EMB_) / 1024), dim3(256), 0, stream, X, Xb);
  hipLaunchKernelGGL(transpose_w3_kernel, dim3(32, 32, 3), dim3(256), 0, stream, Wq, Wk, Wv, Wt3);
  hipLaunchKernelGGL((gemm_xw256_kernel<0>), dim3(ND_ / 256, (B_ * T_) / 256), dim3(512), 131072, stream,
                     Xb, Wt3, Qb);
  hipLaunchKernelGGL((gemm_xw256_kernel<0>), dim3(ND_ / 256, (B_ * T_) / 256), dim3(512), 131072, stream,
                     Xb, Wt3 + (size_t)ND_ * EMB_, Kb);
  hipLaunchKernelGGL((gemm_xw256_kernel<1>), dim3(ND_ / 256, (B_ * T_) / 256), dim3(512), 131072, stream,
                     Xb, Wt3 + (size_t)2 * ND_ * EMB_, Vt);
  hipLaunchKernelGGL(scoretile1088_kernel, dim3(136 * B_), dim3(512), 32768, stream, Qb, Kb, Pb, pm);
  hipLaunchKernelGGL(colreduce_kernel, dim3(16, B_), dim3(128), 0, stream, pm, colinv);
  hipLaunchKernelGGL(vscale_kernel, dim3((B_ * ND_ * T_) / 8 / 256), dim3(256), 0, stream, Vt, colinv);
  hipLaunchKernelGGL(gemm_pv256_kernel, dim3(NTB2 * 4 * B_), dim3(512), 98304, stream, Pb, Vt, out);
}

// Round 19
// 266.886 us; speedup vs baseline: 1.0688x; 1.0688x over previous
//
#include <hip/hip_runtime.h>
#include <hip/hip_bf16.h>

#define B_   8
#define T_   2048
#define EMB_ 1024
#define ND_  1024
#define NTB2 8      // T_/256

typedef __attribute__((ext_vector_type(8))) short   bf8_t;   // 8 bf16 elements (4 VGPRs)
typedef __attribute__((ext_vector_type(4))) float   f32x4;

__device__ __forceinline__ unsigned short f2bf(float f) {
  union { float f; unsigned int u; } c; c.f = f;
  unsigned int u = c.u;
  unsigned int r = (u + 0x7FFFu + ((u >> 16) & 1u)) >> 16;
  return (unsigned short)r;
}

__device__ __forceinline__ float bf2f(unsigned short b) {
  union { unsigned int u; float f; } c; c.u = ((unsigned int)b) << 16;
  return c.f;
}

__device__ __forceinline__ void gload_lds16(const unsigned short* g, unsigned short* l) {
  __builtin_amdgcn_global_load_lds(
      (const __attribute__((address_space(1))) unsigned int*)g,
      (__attribute__((address_space(3))) unsigned int*)l,
      16, 0, 0);
}

__device__ __forceinline__ void tri_decode(int p, int& tblk, int& sblk) {
  int t = (int)((sqrtf(8.0f * (float)p + 1.0f) - 1.0f) * 0.5f);
  while ((t + 1) * (t + 2) / 2 <= p) ++t;
  while (t * (t + 1) / 2 > p) --t;
  tblk = t;
  sblk = p - t * (t + 1) / 2;
}

#define SB0() __builtin_amdgcn_sched_barrier(0)
#define BAR() __builtin_amdgcn_s_barrier()

// Stage one 128x64 bf16 half-tile (8192 shorts = 16 KiB; 2 gloads/wave).
// Dest LDS linear; source column pre-XOR-swizzled so
// lds[row][ce] == G[row][k0 + (ce ^ ((row&7)<<3))].
__device__ __forceinline__ void stage_half(const unsigned short* __restrict__ g, int lda,
                                           unsigned short* lhalf, int wave, int lane) {
  const int r3 = lane >> 3, c3 = lane & 7;
  const int colsw = ((c3 ^ r3) << 3);
#pragma unroll
  for (int j = 0; j < 2; ++j) {
    const int row = wave * 8 + r3 + 64 * j;
    gload_lds16(g + (size_t)row * lda + colsw, lhalf + wave * 512 + j * 4096);
  }
}

// Read one bf16x8 MFMA fragment at half-local row r, K-subtile ks, undoing swizzle.
__device__ __forceinline__ bf8_t read_frag(const unsigned short* half, int r, int ks, int lane) {
  const int col = (((ks) << 5) + ((lane >> 4) << 3)) ^ ((r & 7) << 3);
  return *(const bf8_t*)(half + r * 64 + col);
}

// Epilogue LDS swizzle for 256-B rows, 16-B granules.
__device__ __forceinline__ int swz_ep2(int r) { return (r & 7) << 4; }
// 512-B-row variant.
__device__ __forceinline__ int swz_ep(int x) { return ((x >> 1) & 7) << 4; }

// ---------------- X -> bf16 ----------------
__global__ void __launch_bounds__(256) cvt_x_kernel(const float* __restrict__ in,
                                                    unsigned short* __restrict__ out) {
  const int i = (blockIdx.x * 256 + threadIdx.x) * 4;
  float4 v = *(const float4*)(in + i);
  ushort4 o = make_ushort4(f2bf(v.x), f2bf(v.y), f2bf(v.z), f2bf(v.w));
  *(ushort4*)(out + i) = o;
}

// ---------------- W [K][N] f32 -> Wt3 rows [N][K] bf16 (z selects source) ----------------
__global__ void __launch_bounds__(256) transpose_w3_kernel(const float* __restrict__ Wq,
                                                           const float* __restrict__ Wk,
                                                           const float* __restrict__ Wv,
                                                           unsigned short* __restrict__ Wt3) {
  __shared__ unsigned short tile[32][33];
  const int z = blockIdx.z;
  const float* W = (z == 0) ? Wq : (z == 1) ? Wk : Wv;
  const float cscale = (z == 0) ? 0.03125f : 1.0f;
  unsigned short* Wt = Wt3 + (size_t)z * ND_ * EMB_;
  const int n0 = blockIdx.x * 32, k0 = blockIdx.y * 32;
  const int tx = threadIdx.x & 31, ty = threadIdx.x >> 5;
#pragma unroll
  for (int r = 0; r < 32; r += 8) {
    float v = W[(size_t)(k0 + ty + r) * ND_ + n0 + tx];
    tile[tx][ty + r] = f2bf(v * cscale);
  }
  __syncthreads();
#pragma unroll
  for (int r = 0; r < 32; r += 8) {
    Wt[(size_t)(n0 + ty + r) * EMB_ + k0 + tx] = tile[ty + r][tx];
  }
}

// ================= shared MFMA quad macros =================
#define MFMA_QUAD(MB, AF, AOFF) do { \
  __builtin_amdgcn_s_setprio(1); \
  _Pragma("unroll") \
  for (int mi = 0; mi < 2; ++mi) \
    _Pragma("unroll") \
    for (int nf = 0; nf < 4; ++nf) \
      _Pragma("unroll") \
      for (int ks = 0; ks < 2; ++ks) \
        acc[(MB) * 2 + mi][nf] = __builtin_amdgcn_mfma_f32_16x16x32_bf16( \
            (AF)[(AOFF) + mi][ks], bfr[nf][ks], acc[(MB) * 2 + mi][nf], 0, 0, 0); \
  __builtin_amdgcn_s_setprio(0); \
} while (0)

#define MFMA_Q8(MB) do { \
  __builtin_amdgcn_s_setprio(1); \
  _Pragma("unroll") \
  for (int nf = 0; nf < 4; ++nf) \
    _Pragma("unroll") \
    for (int ks = 0; ks < 2; ++ks) \
      acc[(MB)][nf] = __builtin_amdgcn_mfma_f32_16x16x32_bf16( \
          af[(MB)][ks], bfr[nf][ks], acc[(MB)][nf], 0, 0, 0); \
  __builtin_amdgcn_s_setprio(0); \
} while (0)

// 4-MFMA quad for the 128x128 tile (acc[4][2], nf in 0..1).
#define MFMA_Q4(MB) do { \
  __builtin_amdgcn_s_setprio(1); \
  _Pragma("unroll") \
  for (int nf = 0; nf < 2; ++nf) \
    _Pragma("unroll") \
    for (int ks = 0; ks < 2; ++ks) \
      acc[(MB)][nf] = __builtin_amdgcn_mfma_f32_16x16x32_bf16( \
          af[(MB)][ks], bfr[nf][ks], acc[(MB)][nf], 0, 0, 0); \
  __builtin_amdgcn_s_setprio(0); \
} while (0)

// ================= 256x256 8-phase core, distance-2 prefetch (proven; xw) =========
#define LDSA(d, h) (lds256 + ((d) * 2 + (h)) * 8192)
#define LDSB(d, h) (lds256 + 32768 + ((d) * 2 + (h)) * 8192)

#define GEMM256_LOOP(ABASE, BBASE, LDK) \
  stage_half((ABASE),                             (LDK), LDSA(0, 0), wave, lane); \
  stage_half((ABASE) + (size_t)128 * (LDK),       (LDK), LDSA(0, 1), wave, lane); \
  stage_half((BBASE),                             (LDK), LDSB(0, 0), wave, lane); \
  stage_half((BBASE) + (size_t)128 * (LDK),       (LDK), LDSB(0, 1), wave, lane); \
  stage_half((BBASE) + 64,                        (LDK), LDSB(1, 0), wave, lane); \
  stage_half((BBASE) + (size_t)128 * (LDK) + 64,  (LDK), LDSB(1, 1), wave, lane); \
  stage_half((ABASE) + 64,                        (LDK), LDSA(1, 0), wave, lane); \
  stage_half((ABASE) + (size_t)128 * (LDK) + 64,  (LDK), LDSA(1, 1), wave, lane); \
  asm volatile("s_waitcnt vmcnt(8)" ::: "memory"); \
  SB0(); BAR(); SB0(); \
  for (int t = 0; t < 16; ++t) { \
    const int d = t & 1; \
    const unsigned short* Ah = LDSA(d, wm); \
    const unsigned short* Bh = LDSB(d, wn >> 1); \
    bf8_t bfr[4][2], af[4][2]; \
    _Pragma("unroll") \
    for (int nf = 0; nf < 4; ++nf) \
      _Pragma("unroll") \
      for (int ks = 0; ks < 2; ++ks) bfr[nf][ks] = read_frag(Bh, brow + nf * 16, ks, lane); \
    _Pragma("unroll") \
    for (int mf = 0; mf < 4; ++mf) \
      _Pragma("unroll") \
      for (int ks = 0; ks < 2; ++ks) af[mf][ks] = read_frag(Ah, arow + mf * 16, ks, lane); \
    SB0(); BAR(); SB0(); \
    MFMA_QUAD(0, af, 0); \
    SB0(); \
    asm volatile("s_waitcnt lgkmcnt(0)" ::: "memory"); \
    SB0(); BAR(); SB0(); \
    if (t < 14) { \
      stage_half((BBASE) + (size_t)(t + 2) * 64,                     (LDK), LDSB(d, 0), wave, lane); \
      stage_half((BBASE) + (size_t)128 * (LDK) + (size_t)(t + 2) * 64,(LDK), LDSB(d, 1), wave, lane); \
    } \
    SB0(); BAR(); SB0(); \
    MFMA_QUAD(1, af, 2); \
    SB0(); BAR(); SB0(); \
    bf8_t af2[4][2]; \
    _Pragma("unroll") \
    for (int mf = 0; mf < 4; ++mf) \
      _Pragma("unroll") \
      for (int ks = 0; ks < 2; ++ks) af2[mf][ks] = read_frag(Ah, arow + (mf + 4) * 16, ks, lane); \
    SB0(); BAR(); SB0(); \
    MFMA_QUAD(2, af2, 0); \
    SB0(); \
    asm volatile("s_waitcnt lgkmcnt(0)" ::: "memory"); \
    SB0(); BAR(); SB0(); \
    if (t < 14) { \
      stage_half((ABASE) + (size_t)(t + 2) * 64,                     (LDK), LDSA(d, 0), wave, lane); \
      stage_half((ABASE) + (size_t)128 * (LDK) + (size_t)(t + 2) * 64,(LDK), LDSA(d, 1), wave, lane); \
      asm volatile("s_waitcnt vmcnt(8)" ::: "memory"); \
    } else if (t == 14) { \
      asm volatile("s_waitcnt vmcnt(0)" ::: "memory"); \
    } \
    SB0(); BAR(); SB0(); \
    MFMA_QUAD(3, af2, 2); \
    SB0(); BAR(); SB0(); \
  }

// ========== projection GEMM: C = Xb @ Wt^T (proven 3-dispatch form, 128 KiB LDS) ==========
template <int OUTMODE>
__global__ void __launch_bounds__(512, 2)
gemm_xw256_kernel(const unsigned short* __restrict__ A,
                  const unsigned short* __restrict__ Bt,
                  unsigned short* __restrict__ C) {
  extern __shared__ unsigned short lds256[];
  const int tid = threadIdx.x, lane = tid & 63, wave = tid >> 6;
  const int wm = wave >> 2, wn = wave & 3;
  const int m0 = blockIdx.y * 256, n0 = blockIdx.x * 256;
  const unsigned short* Ab = A + (size_t)m0 * EMB_;
  const unsigned short* Bb = Bt + (size_t)n0 * EMB_;
  f32x4 acc[8][4];
#pragma unroll
  for (int i = 0; i < 8; ++i)
#pragma unroll
    for (int j = 0; j < 4; ++j)
#pragma unroll
      for (int q = 0; q < 4; ++q) acc[i][j][q] = 0.f;
  const int arow = lane & 15;
  const int brow = (wn & 1) * 64 + (lane & 15);

  GEMM256_LOOP(Ab, Bb, EMB_)

  const int cc = lane & 15, cr4 = (lane >> 4) << 2;
#pragma unroll
  for (int mf = 0; mf < 8; ++mf)
#pragma unroll
    for (int nf = 0; nf < 4; ++nf)
#pragma unroll
      for (int q = 0; q < 4; ++q) {
        const int r = wm * 128 + mf * 16 + cr4 + q;
        const int c = wn * 64 + nf * 16 + cc;
        const unsigned short bv = f2bf(acc[mf][nf][q]);
        const int byte = (OUTMODE == 1) ? (c * 512 + ((r * 2) ^ swz_ep(c)))
                                        : (r * 512 + ((c * 2) ^ swz_ep(r)));
        lds256[byte >> 1] = bv;
      }
  __syncthreads();
  if (OUTMODE == 0) {
#pragma unroll
    for (int p = 0; p < 16; ++p) {
      const int o = p * 8192 + tid * 16;
      const int ri = o >> 9, cb = o & 511;
      const bf8_t v = *(const bf8_t*)(lds256 + (((o & ~511) | (cb ^ swz_ep(ri))) >> 1));
      *(bf8_t*)(C + (size_t)(m0 + ri) * ND_ + n0 + (cb >> 1)) = v;
    }
  } else {
    const int bb = m0 >> 11, tt0 = m0 & 2047;
#pragma unroll
    for (int p = 0; p < 16; ++p) {
      const int o = p * 8192 + tid * 16;
      const int ci = o >> 9, rb = o & 511;
      const bf8_t v = *(const bf8_t*)(lds256 + (((o & ~511) | (rb ^ swz_ep(ci))) >> 1));
      *(bf8_t*)(C + ((size_t)bb * ND_ + n0 + ci) * T_ + tt0 + (rb >> 1)) = v;
    }
  }
}

// ========== scoretile1088 (r15-proven): BM=128(t) x BN=128(s), 64 KiB, 2/CU ==========
// LDS (shorts): A(d) at d*8192, B(d) at 16384 + d*8192 -> 64 KiB total.
// Ledger/wave: 2 loads per stage_half; 4 loads/K-tile. Prologue 8 -> vmcnt(4).
// Steady: q1 +A(t+2), q2 +B(t+2), q3 vmcnt(4) completes tile t+1.
__global__ void __launch_bounds__(512, 4)
scoretile1088_kernel(const unsigned short* __restrict__ Qb,
                     const unsigned short* __restrict__ Kb,
                     unsigned short* __restrict__ Pp,
                     float* __restrict__ pm) {
  extern __shared__ unsigned short lds256[];
  const int id = blockIdx.x;
  const int b = id & 7;
  int tb, sb;
  tri_decode(id >> 3, tb, sb);
  const int t0 = tb * 128, s0 = sb * 128;
  const int tid = threadIdx.x, lane = tid & 63, wave = tid >> 6;
  const int wm = wave >> 2, wn = wave & 3;
  const int arow = lane & 15;
  const unsigned short* Ab = Qb + ((size_t)b * T_ + t0) * ND_;
  const unsigned short* Bb = Kb + ((size_t)b * T_ + s0) * ND_;
  f32x4 acc[4][2];
#pragma unroll
  for (int i = 0; i < 4; ++i)
#pragma unroll
    for (int j = 0; j < 2; ++j)
#pragma unroll
      for (int q = 0; q < 4; ++q) acc[i][j][q] = 0.f;

  stage_half(Ab,      ND_, lds256,                 wave, lane);  // A t0
  stage_half(Bb,      ND_, lds256 + 16384,         wave, lane);  // B t0
  stage_half(Ab + 64, ND_, lds256 + 8192,          wave, lane);  // A t1
  stage_half(Bb + 64, ND_, lds256 + 16384 + 8192,  wave, lane);  // B t1
  asm volatile("s_waitcnt vmcnt(4)" ::: "memory");
  SB0(); BAR(); SB0();

  for (int t = 0; t < 16; ++t) {
    const int d = t & 1;
    const unsigned short* Ah = lds256 + d * 8192;
    const unsigned short* Bh = lds256 + 16384 + d * 8192;
    bf8_t bfr[2][2], af[4][2];
#pragma unroll
    for (int nf = 0; nf < 2; ++nf)
#pragma unroll
      for (int ks = 0; ks < 2; ++ks)
        bfr[nf][ks] = read_frag(Bh, wn * 32 + nf * 16 + arow, ks, lane);
#pragma unroll
    for (int mf = 0; mf < 4; ++mf)
#pragma unroll
      for (int ks = 0; ks < 2; ++ks)
        af[mf][ks] = read_frag(Ah, wm * 64 + mf * 16 + arow, ks, lane);
    SB0(); BAR(); SB0();
    MFMA_Q4(0);
    SB0();
    asm volatile("s_waitcnt lgkmcnt(0)" ::: "memory");
    SB0(); BAR(); SB0();
    if (t < 14) stage_half(Ab + (size_t)(t + 2) * 64, ND_, lds256 + d * 8192, wave, lane);
    SB0(); BAR(); SB0();
    MFMA_Q4(1);
    SB0(); BAR(); SB0();
    if (t < 14) stage_half(Bb + (size_t)(t + 2) * 64, ND_, lds256 + 16384 + d * 8192, wave, lane);
    SB0(); BAR(); SB0();
    MFMA_Q4(2);
    SB0(); BAR(); SB0();
    if (t < 14)      { asm volatile("s_waitcnt vmcnt(4)" ::: "memory"); }
    else if (t == 14){ asm volatile("s_waitcnt vmcnt(0)" ::: "memory"); }
    SB0(); BAR(); SB0();
    MFMA_Q4(3);
    SB0(); BAR(); SB0();
  }

  // ---- epilogue: P' = exp(S) (masked) into LDS (128x128, 256-B rows) + col sums ----
  __syncthreads();
  const int cc = lane & 15, cr4 = (lane >> 4) << 2;
  const bool diag = (tb == sb);
  float csum[2];
#pragma unroll
  for (int nf = 0; nf < 2; ++nf) csum[nf] = 0.f;
#pragma unroll
  for (int mf = 0; mf < 4; ++mf)
#pragma unroll
    for (int nf = 0; nf < 2; ++nf)
#pragma unroll
      for (int q = 0; q < 4; ++q) {
        const int rr = wm * 64 + mf * 16 + cr4 + q;   // 0..127
        const int c  = wn * 32 + nf * 16 + cc;        // 0..127
        const bool ok = !diag || ((t0 + rr) >= (s0 + c));
        unsigned short bv = 0;
        if (ok) {
          bv = f2bf(__expf(fminf(acc[mf][nf][q], 30.f)));
          csum[nf] += bf2f(bv);
        }
        lds256[(rr * 256 + ((c * 2) ^ swz_ep2(rr))) >> 1] = bv;
      }
  __syncthreads();
  unsigned short* Pbase = Pp + (size_t)b * T_ * T_;
#pragma unroll
  for (int p = 0; p < 4; ++p) {
    const int o = p * 8192 + tid * 16;
    const int ri = o >> 8, cb = o & 255;
    const bf8_t v = *(const bf8_t*)(lds256 + (((o & ~255) | (cb ^ swz_ep2(ri))) >> 1));
    *(bf8_t*)(Pbase + (size_t)(t0 + ri) * T_ + s0 + (cb >> 1)) = v;
  }
#pragma unroll
  for (int nf = 0; nf < 2; ++nf) {
    csum[nf] += __shfl_xor(csum[nf], 16);
    csum[nf] += __shfl_xor(csum[nf], 32);
  }
  __syncthreads();
  float* red = (float*)lds256;   // [2 wm][4 wn][2 nf][16]
  if (lane < 16) {
#pragma unroll
    for (int nf = 0; nf < 2; ++nf)
      red[((wm * 4 + wn) * 2 + nf) * 16 + lane] = csum[nf];
  }
  __syncthreads();
  if (wm == 0 && lane < 16) {
    const size_t base = (((size_t)b * 16 + sb) * 16 + tb) * 128;
#pragma unroll
    for (int nf = 0; nf < 2; ++nf) {
      const float s = red[((0 * 4 + wn) * 2 + nf) * 16 + lane] +
                      red[((1 * 4 + wn) * 2 + nf) * 16 + lane];
      pm[base + wn * 32 + nf * 16 + lane] = s;
    }
  }
}

// ---------------- c_s = 1 / (sum of per-tile column sums), 128-granularity ----------------
__global__ void __launch_bounds__(128) colreduce_kernel(const float* __restrict__ pm,
                                                        float* __restrict__ colinv) {
  const int sb = blockIdx.x, b = blockIdx.y, c = threadIdx.x;
  float l = 0.f;
  for (int tb = sb; tb < 16; ++tb)
    l += pm[(((size_t)b * 16 + sb) * 16 + tb) * 128 + c];
  colinv[(size_t)b * T_ + sb * 128 + c] = 1.0f / l;
}

// ---------------- V''[b][d][s] = Vt[b][d][s] * c[b][s] (in place) ----------------
__global__ void __launch_bounds__(256) vscale_kernel(unsigned short* __restrict__ Vt,
                                                     const float* __restrict__ colinv) {
  const int idx = blockIdx.x * 256 + threadIdx.x;
  const int s8 = (idx * 8) & (T_ - 1);
  const int bd = idx / (T_ / 8);     // b*ND + d
  const int b = bd >> 10;
  unsigned short* p = Vt + (size_t)bd * T_ + s8;
  bf8_t v = *(bf8_t*)p;
#pragma unroll
  for (int j = 0; j < 8; ++j) {
    const float f = bf2f((unsigned short)v[j]) * colinv[(size_t)b * T_ + s8 + j];
    v[j] = (short)f2bf(f);
  }
  *(bf8_t*)p = v;
}

// ========== PV: BM=128 x BN=256, 3 halves/K-tile, distance-2 prefetch (proven) ==========
__device__ __forceinline__ void pv_segment(const unsigned short* __restrict__ Ab,
                                           const unsigned short* __restrict__ Bb,
                                           float* __restrict__ Cb,
                                           int ktiles, unsigned short* lds256,
                                           int lane, int wave) {
  const int wm = wave >> 2, wn = wave & 3;
  const int arow = lane & 15;
  f32x4 acc[4][4];
#pragma unroll
  for (int i = 0; i < 4; ++i)
#pragma unroll
    for (int j = 0; j < 4; ++j)
#pragma unroll
      for (int q = 0; q < 4; ++q) acc[i][j][q] = 0.f;

  stage_half(Ab,                           T_, lds256,                     wave, lane);
  stage_half(Bb,                           T_, lds256 + 16384,             wave, lane);
  stage_half(Bb + (size_t)128 * T_,        T_, lds256 + 16384 + 8192,      wave, lane);
  stage_half(Ab + 64,                      T_, lds256 + 8192,              wave, lane);
  stage_half(Bb + 64,                      T_, lds256 + 16384 + 2 * 8192,  wave, lane);
  stage_half(Bb + (size_t)128 * T_ + 64,   T_, lds256 + 16384 + 3 * 8192,  wave, lane);
  asm volatile("s_waitcnt vmcnt(6)" ::: "memory");
  SB0(); BAR(); SB0();

  for (int t = 0; t < ktiles; ++t) {
    const int d = t & 1;
    const unsigned short* Ah = lds256 + d * 8192;
    const unsigned short* Bh = lds256 + 16384 + (d * 2 + (wn >> 1)) * 8192;
    bf8_t bfr[4][2], af[4][2];
#pragma unroll
    for (int nf = 0; nf < 4; ++nf)
#pragma unroll
      for (int ks = 0; ks < 2; ++ks)
        bfr[nf][ks] = read_frag(Bh, (wn & 1) * 64 + nf * 16 + arow, ks, lane);
#pragma unroll
    for (int mf = 0; mf < 4; ++mf)
#pragma unroll
      for (int ks = 0; ks < 2; ++ks)
        af[mf][ks] = read_frag(Ah, wm * 64 + mf * 16 + arow, ks, lane);
    SB0(); BAR(); SB0();
    MFMA_Q8(0);
    SB0();
    asm volatile("s_waitcnt lgkmcnt(0)" ::: "memory");
    SB0(); BAR(); SB0();
    if (t < ktiles - 2) {
      stage_half(Ab + (size_t)(t + 2) * 64, T_, lds256 + d * 8192, wave, lane);
      stage_half(Bb + (size_t)(t + 2) * 64, T_, lds256 + 16384 + (d * 2) * 8192, wave, lane);
    }
    SB0(); BAR(); SB0();
    MFMA_Q8(1);
    SB0(); BAR(); SB0();
    if (t < ktiles - 2)
      stage_half(Bb + (size_t)128 * T_ + (size_t)(t + 2) * 64, T_, lds256 + 16384 + (d * 2 + 1) * 8192, wave, lane);
    SB0(); BAR(); SB0();
    MFMA_Q8(2);
    SB0(); BAR(); SB0();
    if (t < ktiles - 2)      { asm volatile("s_waitcnt vmcnt(6)" ::: "memory"); }
    else if (t == ktiles - 2){ asm volatile("s_waitcnt vmcnt(0)" ::: "memory"); }
    SB0(); BAR(); SB0();
    MFMA_Q8(3);
    SB0(); BAR(); SB0();
  }

  const int cc = lane & 15, cr4 = (lane >> 4) << 2;
#pragma unroll
  for (int mf = 0; mf < 4; ++mf)
#pragma unroll
    for (int nf = 0; nf < 4; ++nf)
#pragma unroll
      for (int q = 0; q < 4; ++q) {
        const int row = wm * 64 + mf * 16 + cr4 + q;
        const int col = wn * 64 + nf * 16 + cc;
        Cb[(size_t)row * ND_ + col] = acc[mf][nf][q];
      }
}

// Paired triangular PV: block handles t-blocks {pair, 15-pair} -> uniform 34 K-tiles.
__global__ void __launch_bounds__(512, 2)
gemm_pv256_kernel(const unsigned short* __restrict__ Pb,
                  const unsigned short* __restrict__ Vt,
                  float* __restrict__ out) {
  extern __shared__ unsigned short lds256[];
  const int b = blockIdx.x & 7;
  const int pair = (blockIdx.x >> 3) & 7;
  const int ncol = blockIdx.x >> 6;
  const int lane = threadIdx.x & 63, wave = threadIdx.x >> 6;
  const int tbs[2] = {pair, 15 - pair};
#pragma unroll
  for (int si = 0; si < 2; ++si) {
    const int tb = tbs[si];
    const int ktiles = 2 * tb + 2;
    pv_segment(Pb + (size_t)b * T_ * T_ + (size_t)tb * 128 * T_,
               Vt + (size_t)b * ND_ * T_ + (size_t)ncol * 256 * T_,
               out + (size_t)b * T_ * ND_ + (size_t)tb * 128 * ND_ + ncol * 256,
               ktiles, lds256, lane, wave);
  }
}

extern "C" void kernel_launch(void* const* d_in, const int* in_sizes, int n_in,
                              void* d_out, int out_size, void* d_ws, size_t ws_size,
                              hipStream_t stream) {
  const float* X  = (const float*)d_in[0];
  const float* Wq = (const float*)d_in[1];
  const float* Wk = (const float*)d_in[2];
  const float* Wv = (const float*)d_in[3];
  float* out = (float*)d_out;
  (void)in_sizes; (void)n_in; (void)out_size;

  char* ws = (char*)d_ws;
  size_t off = 0;
  auto alloc = [&](size_t bytes) {
    void* p = ws + off;
    off += (bytes + 255) & ~(size_t)255;
    return p;
  };
  unsigned short* Xb  = (unsigned short*)alloc((size_t)B_ * T_ * EMB_ * 2);
  unsigned short* Wt3 = (unsigned short*)alloc((size_t)3 * ND_ * EMB_ * 2);
  unsigned short* Qb  = (unsigned short*)alloc((size_t)B_ * T_ * ND_ * 2);
  unsigned short* Kb  = (unsigned short*)alloc((size_t)B_ * T_ * ND_ * 2);
  unsigned short* Vt  = (unsigned short*)alloc((size_t)B_ * ND_ * T_ * 2);
  float* colinv = (float*)alloc((size_t)B_ * T_ * 4);
  float* pm     = (float*)alloc((size_t)B_ * 16 * 16 * 128 * 4);
  unsigned short* Pb  = (unsigned short*)alloc((size_t)B_ * T_ * T_ * 2);
  if (off > ws_size) return;

  hipFuncSetAttribute((const void*)&gemm_xw256_kernel<0>,
                      hipFuncAttributeMaxDynamicSharedMemorySize, 131072);
  hipFuncSetAttribute((const void*)&gemm_xw256_kernel<1>,
                      hipFuncAttributeMaxDynamicSharedMemorySize, 131072);
  hipFuncSetAttribute((const void*)&scoretile1088_kernel,
                      hipFuncAttributeMaxDynamicSharedMemorySize, 65536);
  hipFuncSetAttribute((const void*)&gemm_pv256_kernel,
                      hipFuncAttributeMaxDynamicSharedMemorySize, 98304);

  hipLaunchKernelGGL(cvt_x_kernel, dim3((B_ * T_ * EMB_) / 1024), dim3(256), 0, stream, X, Xb);
  hipLaunchKernelGGL(transpose_w3_kernel, dim3(32, 32, 3), dim3(256), 0, stream, Wq, Wk, Wv, Wt3);
  hipLaunchKernelGGL((gemm_xw256_kernel<0>), dim3(ND_ / 256, (B_ * T_) / 256), dim3(512), 131072, stream,
                     Xb, Wt3, Qb);
  hipLaunchKernelGGL((gemm_xw256_kernel<0>), dim3(ND_ / 256, (B_ * T_) / 256), dim3(512), 131072, stream,
                     Xb, Wt3 + (size_t)ND_ * EMB_, Kb);
  hipLaunchKernelGGL((gemm_xw256_kernel<1>), dim3(ND_ / 256, (B_ * T_) / 256), dim3(512), 131072, stream,
                     Xb, Wt3 + (size_t)2 * ND_ * EMB_, Vt);
  hipLaunchKernelGGL(scoretile1088_kernel, dim3(136 * B_), dim3(512), 65536, stream, Qb, Kb, Pb, pm);
  hipLaunchKernelGGL(colreduce_kernel, dim3(16, B_), dim3(128), 0, stream, pm, colinv);
  hipLaunchKernelGGL(vscale_kernel, dim3((B_ * ND_ * T_) / 8 / 256), dim3(256), 0, stream, Vt, colinv);
  hipLaunchKernelGGL(gemm_pv256_kernel, dim3(NTB2 * 4 * B_), dim3(512), 98304, stream, Pb, Vt, out);
}